// Round 1
// baseline (433.289 us; speedup 1.0000x reference)
//
#include <hip/hip_runtime.h>
#include <hip/hip_bf16.h>

#define N 8192
#define IN_F 128
#define OUT_F 64
#define LRELU_ALPHA 0.2f
#define NEG_BIG -9000000000000000.0f

typedef __attribute__((ext_vector_type(8))) short short8;
typedef __attribute__((ext_vector_type(4))) float float4v;

__device__ __forceinline__ unsigned short bf16_bits(float x) {
  unsigned u = __builtin_bit_cast(unsigned, x);
  u += 0x7fffu + ((u >> 16) & 1u);  // round-to-nearest-even
  return (unsigned short)(u >> 16);
}

// prep: Wh = h@W (fp32), s1 = Wh@a1, s2 = Wh@a2, WhT bf16 [64][8192]
__global__ __launch_bounds__(256) void prep_kernel(
    const float* __restrict__ h, const float* __restrict__ W,
    const float* __restrict__ a, float* __restrict__ s1,
    float* __restrict__ s2, unsigned short* __restrict__ whT) {
  const int tid = threadIdx.x;
  const int row = blockIdx.x * 4 + (tid >> 6);
  const int k = tid & 63;
  const float* hr = h + row * IN_F;
  float acc = 0.f;
#pragma unroll 8
  for (int c = 0; c < IN_F; ++c) acc = fmaf(hr[c], W[c * OUT_F + k], acc);
  whT[(long)k * N + row] = bf16_bits(acc);
  float p1 = acc * a[k];
  float p2 = acc * a[OUT_F + k];
#pragma unroll
  for (int off = 32; off > 0; off >>= 1) {
    p1 += __shfl_xor(p1, off);
    p2 += __shfl_xor(p2, off);
  }
  if (k == 0) { s1[row] = p1; s2[row] = p2; }
}

// flash-style: 16 rows/block, 4 waves x 2048-col strips, online softmax + bf16 MFMA PV
__global__ __launch_bounds__(256) void gat_kernel(
    const int* __restrict__ adj, const float* __restrict__ s1,
    const float* __restrict__ s2, const unsigned short* __restrict__ whT,
    float* __restrict__ out) {
  __shared__ float lds_acc[4][16][64];
  __shared__ float lds_m[4][16];
  __shared__ float lds_l[4][16];

  const int tid = threadIdx.x;
  const int wave = tid >> 6;
  const int lane = tid & 63;
  const int r16 = lane & 15;   // A-frag / B-frag row index
  const int quad = lane >> 4;  // 0..3, owns k-octet quad*8..quad*8+7
  const int row0 = blockIdx.x * 16;

  const float s1r = s1[row0 + r16];
  const long adj_base = (long)(row0 + r16) * N;

  float m = NEG_BIG;
  float lsum = 0.f;
  float4v acc0 = {0.f, 0.f, 0.f, 0.f};
  float4v acc1 = {0.f, 0.f, 0.f, 0.f};
  float4v acc2 = {0.f, 0.f, 0.f, 0.f};
  float4v acc3 = {0.f, 0.f, 0.f, 0.f};

  const int jbase = wave * 2048;
  for (int t = 0; t < 64; ++t) {
    const int j0 = jbase + t * 32 + quad * 8;  // this lane's 8 columns
    // adj tile in A-frag layout: row r16, cols j0..j0+7
    const int4* ap = (const int4*)(adj + adj_base + j0);
    const int4 a0 = ap[0];
    const int4 a1 = ap[1];
    const float4* sp = (const float4*)(s2 + j0);
    const float4 s20 = sp[0], s21 = sp[1];
    float se[8] = {s20.x, s20.y, s20.z, s20.w, s21.x, s21.y, s21.z, s21.w};
    int am[8] = {a0.x, a0.y, a0.z, a0.w, a1.x, a1.y, a1.z, a1.w};
    float e[8];
    float cmax = NEG_BIG;
#pragma unroll
    for (int i = 0; i < 8; ++i) {
      float tv = s1r + se[i];
      tv = tv > 0.f ? tv : LRELU_ALPHA * tv;
      e[i] = am[i] > 0 ? tv : NEG_BIG;
      cmax = fmaxf(cmax, e[i]);
    }
    // row max across the 4 quads holding this row
    cmax = fmaxf(cmax, __shfl_xor(cmax, 16));
    cmax = fmaxf(cmax, __shfl_xor(cmax, 32));
    const float newm = fmaxf(m, cmax);
    const float alpha = __expf(m - newm);  // ==1 when both NEG_BIG
    m = newm;

    float psum = 0.f;
    short8 afrag;
#pragma unroll
    for (int i = 0; i < 8; ++i) {
      float p = __expf(e[i] - newm);
      psum += p;
      afrag[i] = (short)bf16_bits(p);
    }
    lsum = fmaf(lsum, alpha, psum);

    // alphas for the 4 C-layout rows this lane accumulates (rows quad*4+r)
    const float al0 = __shfl(alpha, quad * 4 + 0);
    const float al1 = __shfl(alpha, quad * 4 + 1);
    const float al2 = __shfl(alpha, quad * 4 + 2);
    const float al3 = __shfl(alpha, quad * 4 + 3);
    acc0[0] *= al0; acc0[1] *= al1; acc0[2] *= al2; acc0[3] *= al3;
    acc1[0] *= al0; acc1[1] *= al1; acc1[2] *= al2; acc1[3] *= al3;
    acc2[0] *= al0; acc2[1] *= al1; acc2[2] *= al2; acc2[3] *= al3;
    acc3[0] *= al0; acc3[1] *= al1; acc3[2] *= al2; acc3[3] *= al3;

    // B-frags: tile tt covers cols tt*16 + r16; k = j0 octet. 16B contiguous loads.
    const unsigned short* bp = whT + (long)r16 * N + j0;
    const short8 b0 = *(const short8*)(bp + 0L * 16 * N);
    const short8 b1 = *(const short8*)(bp + 1L * 16 * N);
    const short8 b2 = *(const short8*)(bp + 2L * 16 * N);
    const short8 b3 = *(const short8*)(bp + 3L * 16 * N);
    acc0 = __builtin_amdgcn_mfma_f32_16x16x32_bf16(afrag, b0, acc0, 0, 0, 0);
    acc1 = __builtin_amdgcn_mfma_f32_16x16x32_bf16(afrag, b1, acc1, 0, 0, 0);
    acc2 = __builtin_amdgcn_mfma_f32_16x16x32_bf16(afrag, b2, acc2, 0, 0, 0);
    acc3 = __builtin_amdgcn_mfma_f32_16x16x32_bf16(afrag, b3, acc3, 0, 0, 0);
  }

  // row-sum l across the 4 quads
  lsum += __shfl_xor(lsum, 16);
  lsum += __shfl_xor(lsum, 32);
  if (lane < 16) {
    lds_m[wave][lane] = m;
    lds_l[wave][lane] = lsum;
  }
  // C-layout: col = lane&15 (within tile), row = quad*4 + reg
#pragma unroll
  for (int reg = 0; reg < 4; ++reg) {
    const int r = quad * 4 + reg;
    lds_acc[wave][r][0 * 16 + r16] = acc0[reg];
    lds_acc[wave][r][1 * 16 + r16] = acc1[reg];
    lds_acc[wave][r][2 * 16 + r16] = acc2[reg];
    lds_acc[wave][r][3 * 16 + r16] = acc3[reg];
  }
  __syncthreads();

  for (int o = tid; o < 16 * 64; o += 256) {
    const int r = o >> 6, k = o & 63;
    const float m0 = lds_m[0][r], m1 = lds_m[1][r];
    const float m2 = lds_m[2][r], m3 = lds_m[3][r];
    const float M = fmaxf(fmaxf(m0, m1), fmaxf(m2, m3));
    const float w0 = __expf(m0 - M), w1 = __expf(m1 - M);
    const float w2 = __expf(m2 - M), w3 = __expf(m3 - M);
    const float L = lds_l[0][r] * w0 + lds_l[1][r] * w1 +
                    lds_l[2][r] * w2 + lds_l[3][r] * w3;
    const float S = lds_acc[0][r][k] * w0 + lds_acc[1][r][k] * w1 +
                    lds_acc[2][r][k] * w2 + lds_acc[3][r][k] * w3;
    const float v = S / L;
    out[(long)(row0 + r) * OUT_F + k] = v > 0.f ? v : expm1f(v);
  }
}

extern "C" void kernel_launch(void* const* d_in, const int* in_sizes, int n_in,
                              void* d_out, int out_size, void* d_ws, size_t ws_size,
                              hipStream_t stream) {
  const float* h = (const float*)d_in[0];
  const int* adj = (const int*)d_in[1];
  const float* W = (const float*)d_in[2];
  const float* a = (const float*)d_in[3];
  float* out = (float*)d_out;

  // ws layout: s1[8192] f32 | s2[8192] f32 | WhT[64*8192] bf16  (~1.1 MB)
  float* s1 = (float*)d_ws;
  float* s2 = s1 + N;
  unsigned short* whT = (unsigned short*)(s2 + N);

  prep_kernel<<<N / 4, 256, 0, stream>>>(h, W, a, s1, s2, whT);
  gat_kernel<<<N / 16, 256, 0, stream>>>(adj, s1, s2, whT, out);
}